// Round 1
// baseline (242.502 us; speedup 1.0000x reference)
//
#include <hip/hip_runtime.h>

// Y_t = U^T * X_t * V  per token, via bf16 MFMA 16x16x32.
// v2: wave-private decomposition.
//   Stage 1: wave w computes T[32w..32w+32)[:] = X_rows @ V, with A-fragments
//            loaded DIRECTLY from global (no X LDS staging), B = swizzled V frags.
//   Exchange: each wave writes its T^T slice to LDS; ONE barrier.
//   Stage 2: wave w computes Y[32w..32w+32)[:] = U^T_rows @ T, A = swizzled U^T
//            frags from global, B = T^T from LDS.

typedef short bf16x8 __attribute__((ext_vector_type(8)));
typedef float f32x4  __attribute__((ext_vector_type(4)));

#define DIM   128
#define TP    136   // T^T LDS pitch (bf16 elems): 272B rows, 16B-aligned, conflict-free
#define NTOK  2048

static __device__ __forceinline__ unsigned short f2bf(float f) {
    union { float f; unsigned u; } v; v.f = f;
    unsigned r = v.u + 0x7FFFu + ((v.u >> 16) & 1u);  // round-nearest-even
    return (unsigned short)(r >> 16);
}

// Build U/V bf16 fragment-swizzled copies in workspace (unchanged from v1).
// Granule g in [0,2048) per matrix: g = (tile*4 + kk)*64 + lane.
// Granule holds 8 bf16: B[k][n] = src[k*128 + n] for n = tile*16 + (lane&15),
// k = kk*32 + (lane>>4)*8 + j, j=0..7. (For U this yields A[m=j1][k=i1] = U[i1*128+j1].)
__global__ void kron_prep_uv(const float* __restrict__ U,
                             const float* __restrict__ V,
                             unsigned short* __restrict__ swz) {
    int g = blockIdx.x * blockDim.x + threadIdx.x;   // 0..4095
    const float* src = (g < 2048) ? V : U;
    int gg   = g & 2047;
    int lane = gg & 63;
    int blk  = gg >> 6;
    int kk   = blk & 3;
    int tile = blk >> 2;
    int n  = tile * 16 + (lane & 15);
    int k0 = kk * 32 + (lane >> 4) * 8;
    bf16x8 v;
#pragma unroll
    for (int j = 0; j < 8; ++j)
        v[j] = (short)f2bf(src[(k0 + j) * DIM + n]);
    *(bf16x8*)(swz + (size_t)g * 8) = v;
}

__global__ __launch_bounds__(256, 4)
void kron_main(const float* __restrict__ x,
               const unsigned short* __restrict__ Vs,   // swizzled V (stage-1 B frags)
               const unsigned short* __restrict__ Us,   // swizzled U^T (stage-2 A frags)
               float* __restrict__ y) {
    __shared__ unsigned short Tt[DIM * TP];   // 34816 B: T^T only (Tt[j2][i1])

    const int t    = blockIdx.x;
    const int tid  = threadIdx.x;
    const int lane = tid & 63;
    const int wave = tid >> 6;     // 0..3: owns X rows / Y rows [32*wave, 32*wave+32)
    const int m16  = lane & 15;
    const int q    = lane >> 4;

    const float* xp = x + (size_t)t * (DIM * DIM);

    // ---- load X row-slice directly into A-fragments (fp32 -> bf16 in regs) ----
    // Frag (mt,kk): lane (m16,q) holds X[32w + mt*16 + m16][kk*32 + q*8 + j], j=0..7.
    // Per (mt,kk) the wave covers 16 rows x 128B contiguous -> fully coalesced.
    bf16x8 af[2][4];
#pragma unroll
    for (int mt = 0; mt < 2; ++mt) {
        const float* rp = xp + (wave * 32 + mt * 16 + m16) * DIM + q * 8;
#pragma unroll
        for (int kk = 0; kk < 4; ++kk) {
            const float4 a = *(const float4*)(rp + kk * 32);
            const float4 b = *(const float4*)(rp + kk * 32 + 4);
            bf16x8 v;
            v[0] = (short)f2bf(a.x); v[1] = (short)f2bf(a.y);
            v[2] = (short)f2bf(a.z); v[3] = (short)f2bf(a.w);
            v[4] = (short)f2bf(b.x); v[5] = (short)f2bf(b.y);
            v[6] = (short)f2bf(b.z); v[7] = (short)f2bf(b.w);
            af[mt][kk] = v;
        }
    }

    // ---- stage 1: T[32w..][:] = X_rows @ V ----
    f32x4 acc[2][8] = {};
#pragma unroll
    for (int kk = 0; kk < 4; ++kk) {
#pragma unroll
        for (int nt = 0; nt < 8; ++nt) {
            const bf16x8 bfv = *(const bf16x8*)(Vs + (size_t)((nt * 4 + kk) * 64 + lane) * 8);
#pragma unroll
            for (int mt = 0; mt < 2; ++mt)
                acc[mt][nt] = __builtin_amdgcn_mfma_f32_16x16x32_bf16(af[mt][kk], bfv, acc[mt][nt], 0, 0, 0);
        }
    }

    // ---- write own T^T slice (bf16): Tt[j2][i1], i1 in [32w, 32w+32) ----
    // C layout: j2 = nt*16 + m16, i1 = 32w + mt*16 + q*4 + r -> 4 contiguous bf16.
#pragma unroll
    for (int mt = 0; mt < 2; ++mt) {
#pragma unroll
        for (int nt = 0; nt < 8; ++nt) {
            const int j2 = nt * 16 + m16;
            const int i1 = wave * 32 + mt * 16 + q * 4;
            unsigned p0 = (unsigned)f2bf(acc[mt][nt][0]) | ((unsigned)f2bf(acc[mt][nt][1]) << 16);
            unsigned p1 = (unsigned)f2bf(acc[mt][nt][2]) | ((unsigned)f2bf(acc[mt][nt][3]) << 16);
            uint2 w; w.x = p0; w.y = p1;
            *(uint2*)&Tt[j2 * TP + i1] = w;
        }
    }
    __syncthreads();   // the only block-wide barrier

    // ---- stage 2: Y[32w..][:] = U^T_rows @ T ----
    f32x4 acc2[2][8] = {};
#pragma unroll
    for (int kk = 0; kk < 4; ++kk) {
        bf16x8 ua[2];
#pragma unroll
        for (int mt = 0; mt < 2; ++mt)
            ua[mt] = *(const bf16x8*)(Us + (size_t)(((wave * 2 + mt) * 4 + kk) * 64 + lane) * 8);
#pragma unroll
        for (int nt = 0; nt < 8; ++nt) {
            const bf16x8 tb = *(const bf16x8*)&Tt[(nt * 16 + m16) * TP + kk * 32 + q * 8];
#pragma unroll
            for (int mt = 0; mt < 2; ++mt)
                acc2[mt][nt] = __builtin_amdgcn_mfma_f32_16x16x32_bf16(ua[mt], tb, acc2[mt][nt], 0, 0, 0);
        }
    }

    // ---- store Y (fp32): j1 = 32w + mt*16 + q*4 + r, j2 = nt*16 + m16 ----
    float* yp = y + (size_t)t * (DIM * DIM);
#pragma unroll
    for (int mt = 0; mt < 2; ++mt) {
#pragma unroll
        for (int r = 0; r < 4; ++r) {
            const int row = wave * 32 + mt * 16 + q * 4 + r;
#pragma unroll
            for (int nt = 0; nt < 8; ++nt)
                yp[row * DIM + nt * 16 + m16] = acc2[mt][nt][r];
        }
    }
}

extern "C" void kernel_launch(void* const* d_in, const int* in_sizes, int n_in,
                              void* d_out, int out_size, void* d_ws, size_t ws_size,
                              hipStream_t stream) {
    const float* x = (const float*)d_in[0];
    const float* U = (const float*)d_in[1];
    const float* V = (const float*)d_in[2];
    float*       y = (float*)d_out;

    unsigned short* swz = (unsigned short*)d_ws;   // [0,16384): V frags; [16384,32768): U frags
    kron_prep_uv<<<16, 256, 0, stream>>>(U, V, swz);
    kron_main<<<NTOK, 256, 0, stream>>>(x, swz, swz + 2048 * 8, y);
}